// Round 7
// baseline (9466.788 us; speedup 1.0000x reference)
//
#include <hip/hip_runtime.h>

#define B_ 2
#define L_ 3584
#define E_ 820
#define H_ 20
#define D_ 41
#define CB_ 7
#define LC_ 512      // L_/CB_
#define TOPK_ 16
#define NSEL_ 112    // TOPK_*CB_
#define SCALE 0.15617376188860607f  // 1/sqrt(41)

typedef unsigned short bfu;

__device__ __forceinline__ float b2f(bfu h) {
    union { unsigned u; float f; } c; c.u = ((unsigned)h) << 16; return c.f;
}
__device__ __forceinline__ bfu f2b(float f) {
    union { float f; unsigned u; } c; c.f = f;
    unsigned u = c.u;
    return (bfu)((u + 0x7fffu + ((u >> 16) & 1u)) >> 16);
}

// ---------------- workspace layout (bytes) — per-batch reuse, ~32.9 MB total ----------------
// R1 holds k32 during [projK -> cmlpK], then q32 during [projQ -> end of batch].
#define NHLD ((size_t)H_ * L_ * D_)        // 2,939,280 elems (one batch)
#define NHCD ((size_t)H_ * LC_ * D_)       // 419,840 elems
#define OFF_R1   ((size_t)0)                         // fp32, 11,757,120 B
#define OFF_V32  (OFF_R1  + NHLD * 4)                // fp32, 11,757,120 B
#define OFF_K16  (OFF_V32 + NHLD * 4)                // bf16,  5,878,560 B
#define OFF_KC   (OFF_K16 + NHLD * 2)                // fp32,  1,679,360 B
#define OFF_VC   (OFF_KC  + NHCD * 4)                // fp32,  1,679,360 B
#define OFF_BS   (OFF_VC  + NHCD * 4)                // fp64,     81,920 B
#define OFF_IDX  (OFF_BS  + (size_t)H_ * LC_ * 8)    // int,       1,280 B
#define WS_NEEDED (OFF_IDX + (size_t)H_ * TOPK_ * 4)

// ================= K-fail: zero the output (diagnostic fallback) =================
__global__ __launch_bounds__(256) void k_fail(float* __restrict__ out, int n) {
    int i = blockIdx.x * 256 + threadIdx.x;
    if (i < n) out[i] = 0.f;
}

// ================= K0: zero block scores (double) =================
__global__ __launch_bounds__(256) void k_zero_d(double* __restrict__ p, int n) {
    int i = blockIdx.x * 256 + threadIdx.x;
    if (i < n) p[i] = 0.0;
}

// ================= K1: one projection (x @ w + b), fp32 out (H,L,D) =================
// grid (224, 4), block 256. 16 rows x 256 cols per block.
__global__ __launch_bounds__(256) void k_proj(
    const float* __restrict__ x, const float* __restrict__ w, const float* __restrict__ bias,
    float* __restrict__ outp, int b)
{
    __shared__ float xs[E_ * 17];   // transposed [e][r], stride 17, 55,760 B
    const int row0 = blockIdx.x * 16;
    for (int i = threadIdx.x; i < 16 * E_; i += 256) {
        int r = i / E_, e = i - r * E_;
        xs[e * 17 + r] = x[((size_t)b * L_ + row0 + r) * E_ + e];
    }
    __syncthreads();
    const int col = blockIdx.y * 256 + threadIdx.x;
    if (col >= E_) return;
    float acc[16];
    const float bb = bias[col];
#pragma unroll
    for (int r = 0; r < 16; r++) acc[r] = bb;
    const float* wp = w + col;
#pragma unroll 2
    for (int e = 0; e < E_; e++) {
        float wval = wp[(size_t)e * E_];
        const float* xr = &xs[e * 17];
#pragma unroll
        for (int r = 0; r < 16; r++) acc[r] = fmaf(xr[r], wval, acc[r]);
    }
    const int h = col / D_, d = col - h * D_;
#pragma unroll
    for (int r = 0; r < 16; r++)
        outp[((size_t)h * L_ + row0 + r) * D_ + d] = acc[r];
}

// ================= K2: compression MLP (fp32), optional bf16 copy of input ===========
// grid (H_*LC_/4), block 256 (4 waves, one row each)
__global__ __launch_bounds__(256) void k_cmlp(
    const float* __restrict__ src32,                  // (H,L,D) fp32
    const float* __restrict__ w1, const float* __restrict__ b1,
    const float* __restrict__ w2, const float* __restrict__ b2,
    float* __restrict__ dstc,                         // (H,Lc,D) fp32
    bfu* __restrict__ dst16)                          // optional bf16 copy of src
{
    __shared__ float in_s[4][CB_ * D_];
    __shared__ float h_s[4][20];
    const int tid = threadIdx.x, lane = tid & 63, wave = tid >> 6;
    const int row = blockIdx.x * 4 + wave;            // h*LC_ + c
    const int h = row / LC_, c = row - h * LC_;
    const size_t base = ((size_t)h * L_ + c * CB_) * D_;
    for (int i = lane; i < CB_ * D_; i += 64) {
        float fv = src32[base + i];
        in_s[wave][i] = fv;
        if (dst16) dst16[base + i] = f2b(fv);
    }
    __syncthreads();
    if (lane < 20) {
        float a = b1[lane];
        for (int i = 0; i < CB_ * D_; i++) a += in_s[wave][i] * w1[i * 20 + lane];
        h_s[wave][lane] = fmaxf(a, 0.f);
    }
    __syncthreads();
    if (lane < D_) {
        float a = b2[lane];
#pragma unroll
        for (int j = 0; j < 20; j++) a += h_s[wave][j] * w2[j * D_ + lane];
        dstc[(size_t)row * D_ + lane] = a;
    }
}

// ================= K3: compressed attention + block scores (fp64) + g0*comp -> out ====
// grid (20, 224), block 256. 16 queries/block; each wave does 4 queries sequentially.
__global__ __launch_bounds__(256) void k_comp(
    const float* __restrict__ q32, const float* __restrict__ kc,
    const float* __restrict__ vc, const float* __restrict__ wg,
    const float* __restrict__ bg, float* __restrict__ outp,
    double* __restrict__ bscore, int b)
{
    __shared__ float q_s[16][D_];
    __shared__ float p_s[4][LC_];
    __shared__ double bs_l[LC_];
    __shared__ float g0_s[16];
    const int h = blockIdx.x;
    const int q0 = blockIdx.y * 16;
    const int tid = threadIdx.x, lane = tid & 63, wave = tid >> 6;

    for (int i = tid; i < 16 * D_; i += 256) {
        int qq = i / D_, d = i - qq * D_;
        q_s[qq][d] = q32[((size_t)h * L_ + q0 + qq) * D_ + d];
    }
    for (int j = tid; j < LC_; j += 256) bs_l[j] = 0.0;
    __syncthreads();

    if (tid < 16) {   // gates (fp32)
        float a0 = bg[0], a1 = bg[1], a2 = bg[2];
        for (int d = 0; d < D_; d++) {
            float qd = q_s[tid][d];
            a0 += qd * wg[d * 3 + 0];
            a1 += qd * wg[d * 3 + 1];
            a2 += qd * wg[d * 3 + 2];
        }
        float gm = fmaxf(a0, fmaxf(a1, a2));
        float e0 = __expf(a0 - gm), e1 = __expf(a1 - gm), e2 = __expf(a2 - gm);
        g0_s[tid] = e0 / (e0 + e1 + e2);
    }
    __syncthreads();

    const float* kcb = kc + (size_t)h * LC_ * D_;
    const float* vcb = vc + (size_t)h * LC_ * D_;

    float bs_acc[8];
#pragma unroll
    for (int r = 0; r < 8; r++) bs_acc[r] = 0.f;

    for (int qq = 0; qq < 4; qq++) {
        const int qrow = wave * 4 + qq;
        float p[8];
        float m = -1e30f;
#pragma unroll
        for (int r = 0; r < 8; r++) {
            int j = r * 64 + lane;
            float s = 0.f;
            for (int d = 0; d < D_; d++) s += q_s[qrow][d] * kcb[(size_t)j * D_ + d];
            p[r] = s * SCALE;
            m = fmaxf(m, p[r]);
        }
        for (int o = 32; o; o >>= 1) m = fmaxf(m, __shfl_xor(m, o));
        float lsum = 0.f;
#pragma unroll
        for (int r = 0; r < 8; r++) { p[r] = expf(p[r] - m); lsum += p[r]; }
        for (int o = 32; o; o >>= 1) lsum += __shfl_xor(lsum, o);
        float inv = 1.f / lsum;
#pragma unroll
        for (int r = 0; r < 8; r++) {
            p[r] *= inv;
            p_s[wave][r * 64 + lane] = p[r];
            bs_acc[r] += p[r];
        }
        __syncthreads();
        if (lane < D_) {
            float acc = 0.f;
            for (int j = 0; j < LC_; j++) acc += p_s[wave][j] * vcb[(size_t)j * D_ + lane];
            outp[((size_t)(b * L_ + q0 + qrow)) * (H_ * D_) + h * D_ + lane] =
                g0_s[qrow] * acc;
        }
        __syncthreads();
    }
#pragma unroll
    for (int r = 0; r < 8; r++) atomicAdd(&bs_l[r * 64 + lane], (double)bs_acc[r]);
    __syncthreads();
    for (int j = tid; j < LC_; j += 256) atomicAdd(&bscore[h * LC_ + j], bs_l[j]);
}

// ================= K4: top-k (per batch, fp64 scores) =================
// grid 20, block 64
__global__ __launch_bounds__(64) void k_topk(const double* __restrict__ bs, int* __restrict__ idxo)
{
    __shared__ double vb_[64];
    __shared__ int ib_[64];
    __shared__ int win;
    const int h = blockIdx.x, lane = threadIdx.x;
    double vals[8];
#pragma unroll
    for (int r = 0; r < 8; r++) vals[r] = bs[h * LC_ + r * 64 + lane];
    for (int t = 0; t < TOPK_; t++) {
        double bv = -1e30; int bi = 0x7fffffff;
#pragma unroll
        for (int r = 0; r < 8; r++) {
            int j = r * 64 + lane;
            bool better = (vals[r] > bv) || (vals[r] == bv && j < bi);
            if (better) { bv = vals[r]; bi = j; }
        }
        vb_[lane] = bv; ib_[lane] = bi;
        __syncthreads();
        if (lane == 0) {
            double best = -1e30; int besti = 0x7fffffff;
            for (int u = 0; u < 64; u++) {
                if (vb_[u] > best || (vb_[u] == best && ib_[u] < besti)) { best = vb_[u]; besti = ib_[u]; }
            }
            idxo[h * TOPK_ + t] = besti;
            win = besti;
        }
        __syncthreads();
        int w = win;
#pragma unroll
        for (int r = 0; r < 8; r++)
            if ((w >> 6) == r && (w & 63) == lane) vals[r] = -1e30;
        __syncthreads();
    }
}

// ================= K5: selected + window attention + gates -> out accumulate ==========
// grid (20, 224), block 256. 16 queries/block; each wave does 4 queries sequentially.
__global__ __launch_bounds__(256) void k_selwin(
    const float* __restrict__ q32, const bfu* __restrict__ k16,
    const float* __restrict__ v32, const int* __restrict__ idxp,
    const float* __restrict__ wg, const float* __restrict__ bg,
    float* __restrict__ outp, int b)
{
    __shared__ float q_s[16][D_];
    __shared__ int rows_s[NSEL_];
    __shared__ float p_s[4][NSEL_];
    __shared__ float g1_s[16];
    __shared__ float pw_s[16][CB_];   // g2-scaled window probabilities
    const int h = blockIdx.x;
    const int q0 = blockIdx.y * 16;
    const int tid = threadIdx.x, lane = tid & 63, wave = tid >> 6;
    const size_t kvbase = (size_t)h * L_ * D_;

    for (int i = tid; i < 16 * D_; i += 256) {
        int qq = i / D_, d = i - qq * D_;
        q_s[qq][d] = q32[((size_t)h * L_ + q0 + qq) * D_ + d];
    }
    if (tid < NSEL_) {
        int t = tid / CB_;
        rows_s[tid] = idxp[h * TOPK_ + t] * CB_ + (tid - t * CB_);
    }
    __syncthreads();

    if (tid < 16) {   // gates + window softmax (x g2)
        float a0 = bg[0], a1 = bg[1], a2 = bg[2];
        for (int d = 0; d < D_; d++) {
            float qd = q_s[tid][d];
            a0 += qd * wg[d * 3 + 0];
            a1 += qd * wg[d * 3 + 1];
            a2 += qd * wg[d * 3 + 2];
        }
        float gm = fmaxf(a0, fmaxf(a1, a2));
        float e0 = __expf(a0 - gm), e1 = __expf(a1 - gm), e2 = __expf(a2 - gm);
        float ginv = 1.f / (e0 + e1 + e2);
        g1_s[tid] = e1 * ginv;
        float g2 = e2 * ginv;
        float sw[CB_];
        float m = -1e30f;
        for (int i = 0; i < CB_; i++) {
            float s = 0.f;
            for (int d = 0; d < D_; d++)
                s += q_s[tid][d] * b2f(k16[kvbase + (size_t)(L_ - CB_ + i) * D_ + d]);
            sw[i] = s * SCALE;
            m = fmaxf(m, sw[i]);
        }
        float lsum = 0.f;
        for (int i = 0; i < CB_; i++) { sw[i] = __expf(sw[i] - m); lsum += sw[i]; }
        float winv = g2 / lsum;
        for (int i = 0; i < CB_; i++) pw_s[tid][i] = sw[i] * winv;
    }
    __syncthreads();

    for (int qq = 0; qq < 4; qq++) {
        const int qrow = wave * 4 + qq;
        float s0 = 0.f;
        {
            int row = rows_s[lane];
            for (int d = 0; d < D_; d++)
                s0 += q_s[qrow][d] * b2f(k16[kvbase + (size_t)row * D_ + d]);
            s0 *= SCALE;
        }
        const bool v1 = (64 + lane) < NSEL_;
        float s1 = -1e30f;
        if (v1) {
            int row = rows_s[64 + lane];
            float s = 0.f;
            for (int d = 0; d < D_; d++)
                s += q_s[qrow][d] * b2f(k16[kvbase + (size_t)row * D_ + d]);
            s1 = s * SCALE;
        }
        float m = fmaxf(s0, s1);
        for (int o = 32; o; o >>= 1) m = fmaxf(m, __shfl_xor(m, o));
        float e0 = __expf(s0 - m);
        float e1 = v1 ? __expf(s1 - m) : 0.f;
        float lsum = e0 + e1;
        for (int o = 32; o; o >>= 1) lsum += __shfl_xor(lsum, o);
        float inv = 1.f / lsum;
        p_s[wave][lane] = e0 * inv;
        if (v1) p_s[wave][64 + lane] = e1 * inv;
        __syncthreads();
        if (lane < D_) {
            float acc = 0.f;
            for (int key = 0; key < NSEL_; key++)
                acc += p_s[wave][key] * v32[kvbase + (size_t)rows_s[key] * D_ + lane];
            float wvv = 0.f;
#pragma unroll
            for (int i = 0; i < CB_; i++)
                wvv += pw_s[qrow][i] * v32[kvbase + (size_t)(L_ - CB_ + i) * D_ + lane];
            float* op = &outp[((size_t)(b * L_ + q0 + qrow)) * (H_ * D_) + h * D_ + lane];
            *op = *op + g1_s[qrow] * acc + wvv;
        }
        __syncthreads();
    }
}

extern "C" void kernel_launch(void* const* d_in, const int* in_sizes, int n_in,
                              void* d_out, int out_size, void* d_ws, size_t ws_size,
                              hipStream_t stream) {
    (void)in_sizes; (void)n_in;
    const float* x  = (const float*)d_in[0];
    const float* wq = (const float*)d_in[1];  const float* bq = (const float*)d_in[2];
    const float* wk = (const float*)d_in[3];  const float* bk = (const float*)d_in[4];
    const float* wv = (const float*)d_in[5];  const float* bv = (const float*)d_in[6];
    const float* w1 = (const float*)d_in[7];  const float* b1 = (const float*)d_in[8];
    const float* w2 = (const float*)d_in[9];  const float* b2 = (const float*)d_in[10];
    const float* wg = (const float*)d_in[11]; const float* bg = (const float*)d_in[12];

    if (d_ws == nullptr || ws_size < WS_NEEDED) {
        k_fail<<<dim3((out_size + 255) / 256), 256, 0, stream>>>((float*)d_out, out_size);
        return;
    }

    char* ws = (char*)d_ws;
    float*  r1   = (float*)(ws + OFF_R1);    // k32 then q32
    float*  v32  = (float*)(ws + OFF_V32);
    bfu*    k16  = (bfu*)(ws + OFF_K16);
    float*  kc   = (float*)(ws + OFF_KC);
    float*  vc   = (float*)(ws + OFF_VC);
    double* bsc  = (double*)(ws + OFF_BS);
    int*    idxp = (int*)(ws + OFF_IDX);
    float*  outp = (float*)d_out;

    for (int b = 0; b < B_; b++) {
        k_zero_d<<<dim3((H_ * LC_ + 255) / 256), 256, 0, stream>>>(bsc, H_ * LC_);
        // K projection (fp32) -> R1
        k_proj<<<dim3(L_ / 16, 4), 256, 0, stream>>>(x, wk, bk, r1, b);
        // kc (fp32) + k16 (bf16 copy)
        k_cmlp<<<dim3(H_ * LC_ / 4), 256, 0, stream>>>(r1, w1, b1, w2, b2, kc, k16);
        // Q projection (fp32) -> R1 (overwrites k32; safe: cmlp already done)
        k_proj<<<dim3(L_ / 16, 4), 256, 0, stream>>>(x, wq, bq, r1, b);
        // V projection (fp32) -> v32
        k_proj<<<dim3(L_ / 16, 4), 256, 0, stream>>>(x, wv, bv, v32, b);
        // vc (fp32)
        k_cmlp<<<dim3(H_ * LC_ / 4), 256, 0, stream>>>(v32, w1, b1, w2, b2, vc, (bfu*)nullptr);
        // compressed attention + fp64 block scores + g0*comp -> out
        k_comp<<<dim3(H_, L_ / 16), 256, 0, stream>>>(r1, kc, vc, wg, bg, outp, bsc, b);
        // top-16
        k_topk<<<dim3(H_), 64, 0, stream>>>(bsc, idxp);
        // selected + window + gates -> out
        k_selwin<<<dim3(H_, L_ / 16), 256, 0, stream>>>(r1, k16, v32, idxp, wg, bg, outp, b);
    }
}

// Round 9
// 3367.336 us; speedup vs baseline: 2.8114x; 2.8114x over previous
//
#include <hip/hip_runtime.h>

#define B_ 2
#define L_ 3584
#define E_ 820
#define H_ 20
#define D_ 41
#define CB_ 7
#define LC_ 512      // L_/CB_
#define TOPK_ 16
#define NSEL_ 112    // TOPK_*CB_
#define SCALE 0.15617376188860607f  // 1/sqrt(41)

typedef unsigned short bfu;

__device__ __forceinline__ float b2f(bfu h) {
    union { unsigned u; float f; } c; c.u = ((unsigned)h) << 16; return c.f;
}
__device__ __forceinline__ bfu f2b(float f) {
    union { float f; unsigned u; } c; c.f = f;
    unsigned u = c.u;
    return (bfu)((u + 0x7fffu + ((u >> 16) & 1u)) >> 16);
}
__device__ __forceinline__ void b2x2(unsigned u, float& a, float& b) {
    union { unsigned u; float f; } c0, c1;
    c0.u = u << 16; c1.u = u & 0xffff0000u;
    a = c0.f; b = c1.f;
}

// ---------------- workspace layout (bytes) — per-batch reuse, ~32.9 MB total ----------------
#define NHLD ((size_t)H_ * L_ * D_)        // 2,939,280 elems (one batch)
#define NHCD ((size_t)H_ * LC_ * D_)       // 419,840 elems
#define OFF_R1   ((size_t)0)                         // fp32, 11,757,120 B (k32 then q32)
#define OFF_V32  (OFF_R1  + NHLD * 4)                // fp32, 11,757,120 B
#define OFF_K16  (OFF_V32 + NHLD * 4)                // bf16,  5,878,560 B
#define OFF_KC   (OFF_K16 + NHLD * 2)                // fp32,  1,679,360 B
#define OFF_VC   (OFF_KC  + NHCD * 4)                // fp32,  1,679,360 B
#define OFF_BS   (OFF_VC  + NHCD * 4)                // fp64,     81,920 B
#define OFF_IDX  (OFF_BS  + (size_t)H_ * LC_ * 8)    // int,       1,280 B
#define WS_NEEDED (OFF_IDX + (size_t)H_ * TOPK_ * 4)

// ================= K-fail: zero the output (diagnostic fallback) =================
__global__ __launch_bounds__(256) void k_fail(float* __restrict__ out, int n) {
    int i = blockIdx.x * 256 + threadIdx.x;
    if (i < n) out[i] = 0.f;
}

// ================= K0: zero block scores (double) =================
__global__ __launch_bounds__(256) void k_zero_d(double* __restrict__ p, int n) {
    int i = blockIdx.x * 256 + threadIdx.x;
    if (i < n) p[i] = 0.0;
}

// ================= K1: one projection (x @ w + b), fp32 out (H,L,D) =================
// grid (224, 4), block 256. 16 rows x 256 cols per block.
__global__ __launch_bounds__(256) void k_proj(
    const float* __restrict__ x, const float* __restrict__ w, const float* __restrict__ bias,
    float* __restrict__ outp, int b)
{
    __shared__ float xs[E_ * 17];   // transposed [e][r], stride 17, 55,760 B
    const int row0 = blockIdx.x * 16;
    for (int i = threadIdx.x; i < 16 * E_; i += 256) {
        int r = i / E_, e = i - r * E_;
        xs[e * 17 + r] = x[((size_t)b * L_ + row0 + r) * E_ + e];
    }
    __syncthreads();
    const int col = blockIdx.y * 256 + threadIdx.x;
    if (col >= E_) return;
    float acc[16];
    const float bb = bias[col];
#pragma unroll
    for (int r = 0; r < 16; r++) acc[r] = bb;
    const float* wp = w + col;
#pragma unroll 2
    for (int e = 0; e < E_; e++) {
        float wval = wp[(size_t)e * E_];
        const float* xr = &xs[e * 17];
#pragma unroll
        for (int r = 0; r < 16; r++) acc[r] = fmaf(xr[r], wval, acc[r]);
    }
    const int h = col / D_, d = col - h * D_;
#pragma unroll
    for (int r = 0; r < 16; r++)
        outp[((size_t)h * L_ + row0 + r) * D_ + d] = acc[r];
}

// ================= K2: compression MLP (fp32), optional bf16 copy of input ===========
// grid (H_*LC_/4), block 256 (4 waves, one row each)
__global__ __launch_bounds__(256) void k_cmlp(
    const float* __restrict__ src32,
    const float* __restrict__ w1, const float* __restrict__ b1,
    const float* __restrict__ w2, const float* __restrict__ b2,
    float* __restrict__ dstc, bfu* __restrict__ dst16)
{
    __shared__ float in_s[4][CB_ * D_];
    __shared__ float h_s[4][20];
    const int tid = threadIdx.x, lane = tid & 63, wave = tid >> 6;
    const int row = blockIdx.x * 4 + wave;            // h*LC_ + c
    const int h = row / LC_, c = row - h * LC_;
    const size_t base = ((size_t)h * L_ + c * CB_) * D_;
    for (int i = lane; i < CB_ * D_; i += 64) {
        float fv = src32[base + i];
        in_s[wave][i] = fv;
        if (dst16) dst16[base + i] = f2b(fv);
    }
    __syncthreads();
    if (lane < 20) {
        float a = b1[lane];
        for (int i = 0; i < CB_ * D_; i++) a += in_s[wave][i] * w1[i * 20 + lane];
        h_s[wave][lane] = fmaxf(a, 0.f);
    }
    __syncthreads();
    if (lane < D_) {
        float a = b2[lane];
#pragma unroll
        for (int j = 0; j < 20; j++) a += h_s[wave][j] * w2[j * D_ + lane];
        dstc[(size_t)row * D_ + lane] = a;
    }
}

// ================= K3 v3: compressed attention, LDS-staged, fp32 scores =================
// grid (20, 224), block 256. 16 queries/block, 4 per wave.
// Scores from fp32 kc staged in 2 half-tiles of 256 keys (ranking-exact).
// LDS region reuse: kcs f32[256][44] (x2 stages) -> bs_l f32[512] -> vcT bf16[41][516]
__global__ __launch_bounds__(256) void k_comp(
    const float* __restrict__ q32, const float* __restrict__ kc,
    const float* __restrict__ vc, const float* __restrict__ wg,
    const float* __restrict__ bg, float* __restrict__ outp,
    double* __restrict__ bscore, int b)
{
    __shared__ __align__(16) char region[256 * 44 * 4];   // 45,056 B
    __shared__ __align__(16) bfu p_s[16][LC_];            // 16,384 B
    __shared__ __align__(16) float q_s[16][44];           // 2,816 B
    __shared__ float g0_s[16];                            // total 64,320 B
    const int h = blockIdx.x;
    const int q0 = blockIdx.y * 16;
    const int tid = threadIdx.x, lane = tid & 63, wave = tid >> 6;
    const float* kcb = kc + (size_t)h * LC_ * D_;
    const float* vcb = vc + (size_t)h * LC_ * D_;

    for (int i = tid; i < 16 * D_; i += 256) {
        int qq = i / D_, d = i - qq * D_;
        q_s[qq][d] = q32[((size_t)h * L_ + q0 + qq) * D_ + d];
    }
    __syncthreads();

    if (tid < 16) {   // gates (fp32)
        float a0 = bg[0], a1 = bg[1], a2 = bg[2];
        for (int d = 0; d < D_; d++) {
            float qd = q_s[tid][d];
            a0 += qd * wg[d * 3 + 0];
            a1 += qd * wg[d * 3 + 1];
            a2 += qd * wg[d * 3 + 2];
        }
        float gm = fmaxf(a0, fmaxf(a1, a2));
        float e0 = __expf(a0 - gm), e1 = __expf(a1 - gm), e2 = __expf(a2 - gm);
        g0_s[tid] = e0 / (e0 + e1 + e2);
    }

    // ---- scores (fp32 kc): two half-tiles of 256 keys ----
    float s[8][4];
#pragma unroll
    for (int r = 0; r < 8; r++)
#pragma unroll
        for (int qi = 0; qi < 4; qi++) s[r][qi] = 0.f;

    float* kcs = (float*)region;       // [256][44] fp32
    for (int stage = 0; stage < 2; stage++) {
        for (int i = tid; i < 256 * D_; i += 256) {
            int j = i / D_, d = i - j * D_;
            kcs[j * 44 + d] = kcb[(size_t)(stage * 256) * D_ + i];
        }
        __syncthreads();
#pragma unroll
        for (int rl = 0; rl < 4; rl++) {
            const int r = stage * 4 + rl;
            const float* krow = &kcs[(rl * 64 + lane) * 44];
            for (int dc = 0; dc < 10; dc++) {
                float4 kv = *(const float4*)&krow[dc * 4];
#pragma unroll
                for (int qi = 0; qi < 4; qi++) {
                    float4 qv = *(const float4*)&q_s[wave * 4 + qi][dc * 4];
                    s[r][qi] += qv.x * kv.x + qv.y * kv.y + qv.z * kv.z + qv.w * kv.w;
                }
            }
            float kt = krow[40];
#pragma unroll
            for (int qi = 0; qi < 4; qi++) s[r][qi] += q_s[wave * 4 + qi][40] * kt;
        }
        __syncthreads();               // region dead before restage
    }

    float bs_acc[8];
#pragma unroll
    for (int r = 0; r < 8; r++) bs_acc[r] = 0.f;
#pragma unroll
    for (int qi = 0; qi < 4; qi++) {
        float m = -1e30f;
#pragma unroll
        for (int r = 0; r < 8; r++) { s[r][qi] *= SCALE; m = fmaxf(m, s[r][qi]); }
        for (int o = 32; o; o >>= 1) m = fmaxf(m, __shfl_xor(m, o));
        float e[8], lsum = 0.f;
#pragma unroll
        for (int r = 0; r < 8; r++) { e[r] = expf(s[r][qi] - m); lsum += e[r]; }
        for (int o = 32; o; o >>= 1) lsum += __shfl_xor(lsum, o);
        float inv = 1.f / lsum;
#pragma unroll
        for (int r = 0; r < 8; r++) {
            float p = e[r] * inv;
            p_s[wave * 4 + qi][r * 64 + lane] = f2b(p);
            bs_acc[r] += p;            // fp32, pre-rounding (ranking-exact)
        }
    }

    // ---- block scores: LDS f32 reduce -> global double atomics ----
    float* bs_l = (float*)region;
    for (int j = tid; j < LC_; j += 256) bs_l[j] = 0.f;
    __syncthreads();
#pragma unroll
    for (int r = 0; r < 8; r++) atomicAdd(&bs_l[r * 64 + lane], bs_acc[r]);
    __syncthreads();
    for (int j = tid; j < LC_; j += 256) atomicAdd(&bscore[h * LC_ + j], (double)bs_l[j]);
    __syncthreads();                   // bs_l dead

    // ---- re-stage region as vc^T (bf16, pad 516) ----
    bfu* vcT = (bfu*)region;
    for (int i = tid; i < LC_ * D_; i += 256) {
        int j = i / D_, d = i - j * D_;
        vcT[d * 516 + j] = f2b(vcb[i]);
    }
    __syncthreads();

    // ---- PV -> out = g0 * attn_comp (overwrite) ----
    if (lane < D_) {
        float acc[4] = {0.f, 0.f, 0.f, 0.f};
        for (int jc = 0; jc < LC_; jc += 4) {
            uint2 vv = *(const uint2*)&vcT[lane * 516 + jc];
            float v0, v1, v2, v3;
            b2x2(vv.x, v0, v1); b2x2(vv.y, v2, v3);
#pragma unroll
            for (int qi = 0; qi < 4; qi++) {
                uint2 pp = *(const uint2*)&p_s[wave * 4 + qi][jc];
                float p0, p1, p2, p3;
                b2x2(pp.x, p0, p1); b2x2(pp.y, p2, p3);
                acc[qi] += p0 * v0 + p1 * v1 + p2 * v2 + p3 * v3;
            }
        }
#pragma unroll
        for (int qi = 0; qi < 4; qi++) {
            int row = wave * 4 + qi;
            outp[((size_t)(b * L_ + q0 + row)) * (H_ * D_) + h * D_ + lane] =
                g0_s[row] * acc[qi];
        }
    }
}

// ================= K4: top-k (per batch, fp64 scores) =================
// grid 20, block 64
__global__ __launch_bounds__(64) void k_topk(const double* __restrict__ bs, int* __restrict__ idxo)
{
    __shared__ double vb_[64];
    __shared__ int ib_[64];
    __shared__ int win;
    const int h = blockIdx.x, lane = threadIdx.x;
    double vals[8];
#pragma unroll
    for (int r = 0; r < 8; r++) vals[r] = bs[h * LC_ + r * 64 + lane];
    for (int t = 0; t < TOPK_; t++) {
        double bv = -1e30; int bi = 0x7fffffff;
#pragma unroll
        for (int r = 0; r < 8; r++) {
            int j = r * 64 + lane;
            bool better = (vals[r] > bv) || (vals[r] == bv && j < bi);
            if (better) { bv = vals[r]; bi = j; }
        }
        vb_[lane] = bv; ib_[lane] = bi;
        __syncthreads();
        if (lane == 0) {
            double best = -1e30; int besti = 0x7fffffff;
            for (int u = 0; u < 64; u++) {
                if (vb_[u] > best || (vb_[u] == best && ib_[u] < besti)) { best = vb_[u]; besti = ib_[u]; }
            }
            idxo[h * TOPK_ + t] = besti;
            win = besti;
        }
        __syncthreads();
        int w = win;
#pragma unroll
        for (int r = 0; r < 8; r++)
            if ((w >> 6) == r && (w & 63) == lane) vals[r] = -1e30;
        __syncthreads();
    }
}

// ================= K5 v2: selected + window attention, LDS-staged =================
// grid (20, 224), block 256. 16 queries/block, 4 per wave.
__global__ __launch_bounds__(256) void k_selwin(
    const float* __restrict__ q32, const bfu* __restrict__ k16,
    const float* __restrict__ v32, const int* __restrict__ idxp,
    const float* __restrict__ wg, const float* __restrict__ bg,
    float* __restrict__ outp, int b)
{
    __shared__ __align__(16) bfu ks_s[119][44];      // 112 sel + 7 window keys
    __shared__ __align__(16) float vsT[D_][130];     // fp32 v^T, pad 130
    __shared__ __align__(16) float q_s[16][44];
    __shared__ __align__(16) bfu p_s[16][NSEL_];
    __shared__ int rows_s[NSEL_];
    __shared__ float g1_s[16];
    __shared__ float pw_s[16][CB_];                  // g2-scaled window probs
    const int h = blockIdx.x;
    const int q0 = blockIdx.y * 16;
    const int tid = threadIdx.x, lane = tid & 63, wave = tid >> 6;
    const size_t kvbase = (size_t)h * L_ * D_;

    for (int i = tid; i < 16 * D_; i += 256) {
        int qq = i / D_, d = i - qq * D_;
        q_s[qq][d] = q32[((size_t)h * L_ + q0 + qq) * D_ + d];
    }
    if (tid < NSEL_) {
        int t = tid / CB_;
        rows_s[tid] = idxp[h * TOPK_ + t] * CB_ + (tid - t * CB_);
    }
    __syncthreads();

    for (int i = tid; i < 119 * D_; i += 256) {
        int key = i / D_, d = i - key * D_;
        int row = (key < NSEL_) ? rows_s[key] : (L_ - CB_ + (key - NSEL_));
        ks_s[key][d] = k16[kvbase + (size_t)row * D_ + d];
        vsT[d][key]  = v32[kvbase + (size_t)row * D_ + d];
    }
    __syncthreads();

    if (tid < 16) {   // gates + window softmax (x g2)
        float a0 = bg[0], a1 = bg[1], a2 = bg[2];
        for (int d = 0; d < D_; d++) {
            float qd = q_s[tid][d];
            a0 += qd * wg[d * 3 + 0];
            a1 += qd * wg[d * 3 + 1];
            a2 += qd * wg[d * 3 + 2];
        }
        float gm = fmaxf(a0, fmaxf(a1, a2));
        float e0 = __expf(a0 - gm), e1 = __expf(a1 - gm), e2 = __expf(a2 - gm);
        float ginv = 1.f / (e0 + e1 + e2);
        g1_s[tid] = e1 * ginv;
        float g2 = e2 * ginv;
        float sw[CB_];
        float m = -1e30f;
        for (int i = 0; i < CB_; i++) {
            float ss = 0.f;
            for (int d = 0; d < D_; d++) ss += q_s[tid][d] * b2f(ks_s[NSEL_ + i][d]);
            sw[i] = ss * SCALE;
            m = fmaxf(m, sw[i]);
        }
        float lsum = 0.f;
        for (int i = 0; i < CB_; i++) { sw[i] = __expf(sw[i] - m); lsum += sw[i]; }
        float winv = g2 / lsum;
        for (int i = 0; i < CB_; i++) pw_s[tid][i] = sw[i] * winv;
    }
    __syncthreads();

    const bool v1 = (64 + lane) < NSEL_;
    const int row1c = v1 ? (64 + lane) : 0;
    float s0[4] = {0, 0, 0, 0}, s1[4] = {0, 0, 0, 0};
    for (int dc = 0; dc < 10; dc++) {
        float4 qv[4];
#pragma unroll
        for (int qi = 0; qi < 4; qi++) qv[qi] = *(const float4*)&q_s[wave * 4 + qi][dc * 4];
        uint2 ra = *(const uint2*)&ks_s[lane][dc * 4];
        uint2 rb = *(const uint2*)&ks_s[row1c][dc * 4];
        float a0, a1, a2, a3, c0, c1, c2, c3;
        b2x2(ra.x, a0, a1); b2x2(ra.y, a2, a3);
        b2x2(rb.x, c0, c1); b2x2(rb.y, c2, c3);
#pragma unroll
        for (int qi = 0; qi < 4; qi++) {
            s0[qi] += qv[qi].x * a0 + qv[qi].y * a1 + qv[qi].z * a2 + qv[qi].w * a3;
            s1[qi] += qv[qi].x * c0 + qv[qi].y * c1 + qv[qi].z * c2 + qv[qi].w * c3;
        }
    }
    {
        float ka = b2f(ks_s[lane][40]);
        float kb = b2f(ks_s[row1c][40]);
#pragma unroll
        for (int qi = 0; qi < 4; qi++) {
            float qt = q_s[wave * 4 + qi][40];
            s0[qi] += qt * ka; s1[qi] += qt * kb;
        }
    }
#pragma unroll
    for (int qi = 0; qi < 4; qi++) {
        float a0 = s0[qi] * SCALE;
        float a1 = v1 ? s1[qi] * SCALE : -1e30f;
        float m = fmaxf(a0, a1);
        for (int o = 32; o; o >>= 1) m = fmaxf(m, __shfl_xor(m, o));
        float e0 = __expf(a0 - m);
        float e1 = v1 ? __expf(a1 - m) : 0.f;
        float lsum = e0 + e1;
        for (int o = 32; o; o >>= 1) lsum += __shfl_xor(lsum, o);
        float inv = 1.f / lsum;
        p_s[wave * 4 + qi][lane] = f2b(e0 * inv);
        if (v1) p_s[wave * 4 + qi][64 + lane] = f2b(e1 * inv);
    }
    __syncthreads();

    if (lane < D_) {
        float acc[4] = {0, 0, 0, 0};
        for (int jc = 0; jc < NSEL_; jc += 4) {
            float2 va = *(const float2*)&vsT[lane][jc];
            float2 vb = *(const float2*)&vsT[lane][jc + 2];
#pragma unroll
            for (int qi = 0; qi < 4; qi++) {
                uint2 pp = *(const uint2*)&p_s[wave * 4 + qi][jc];
                float p0, p1, p2, p3;
                b2x2(pp.x, p0, p1); b2x2(pp.y, p2, p3);
                acc[qi] += p0 * va.x + p1 * va.y + p2 * vb.x + p3 * vb.y;
            }
        }
#pragma unroll
        for (int qi = 0; qi < 4; qi++) {
            int row = wave * 4 + qi;
            float wvv = 0.f;
#pragma unroll
            for (int i = 0; i < CB_; i++) wvv += pw_s[row][i] * vsT[lane][NSEL_ + i];
            float* op = &outp[((size_t)(b * L_ + q0 + row)) * (H_ * D_) + h * D_ + lane];
            *op = *op + g1_s[row] * acc[qi] + wvv;
        }
    }
}

extern "C" void kernel_launch(void* const* d_in, const int* in_sizes, int n_in,
                              void* d_out, int out_size, void* d_ws, size_t ws_size,
                              hipStream_t stream) {
    (void)in_sizes; (void)n_in;
    const float* x  = (const float*)d_in[0];
    const float* wq = (const float*)d_in[1];  const float* bq = (const float*)d_in[2];
    const float* wk = (const float*)d_in[3];  const float* bk = (const float*)d_in[4];
    const float* wv = (const float*)d_in[5];  const float* bv = (const float*)d_in[6];
    const float* w1 = (const float*)d_in[7];  const float* b1 = (const float*)d_in[8];
    const float* w2 = (const float*)d_in[9];  const float* b2 = (const float*)d_in[10];
    const float* wg = (const float*)d_in[11]; const float* bg = (const float*)d_in[12];

    if (d_ws == nullptr || ws_size < WS_NEEDED) {
        k_fail<<<dim3((out_size + 255) / 256), 256, 0, stream>>>((float*)d_out, out_size);
        return;
    }

    char* ws = (char*)d_ws;
    float*  r1   = (float*)(ws + OFF_R1);    // k32 then q32
    float*  v32  = (float*)(ws + OFF_V32);
    bfu*    k16  = (bfu*)(ws + OFF_K16);
    float*  kc   = (float*)(ws + OFF_KC);
    float*  vc   = (float*)(ws + OFF_VC);
    double* bsc  = (double*)(ws + OFF_BS);
    int*    idxp = (int*)(ws + OFF_IDX);
    float*  outp = (float*)d_out;

    for (int b = 0; b < B_; b++) {
        k_zero_d<<<dim3((H_ * LC_ + 255) / 256), 256, 0, stream>>>(bsc, H_ * LC_);
        k_proj<<<dim3(L_ / 16, 4), 256, 0, stream>>>(x, wk, bk, r1, b);
        k_cmlp<<<dim3(H_ * LC_ / 4), 256, 0, stream>>>(r1, w1, b1, w2, b2, kc, k16);
        k_proj<<<dim3(L_ / 16, 4), 256, 0, stream>>>(x, wq, bq, r1, b);
        k_proj<<<dim3(L_ / 16, 4), 256, 0, stream>>>(x, wv, bv, v32, b);
        k_cmlp<<<dim3(H_ * LC_ / 4), 256, 0, stream>>>(v32, w1, b1, w2, b2, vc, (bfu*)nullptr);
        k_comp<<<dim3(H_, L_ / 16), 256, 0, stream>>>(r1, kc, vc, wg, bg, outp, bsc, b);
        k_topk<<<dim3(H_), 64, 0, stream>>>(bsc, idxp);
        k_selwin<<<dim3(H_, L_ / 16), 256, 0, stream>>>(r1, k16, v32, idxp, wg, bg, outp, b);
    }
}

// Round 10
// 2651.454 us; speedup vs baseline: 3.5704x; 1.2700x over previous
//
#include <hip/hip_runtime.h>

#define B_ 2
#define L_ 3584
#define E_ 820
#define H_ 20
#define D_ 41
#define CB_ 7
#define LC_ 512      // L_/CB_
#define TOPK_ 16
#define NSEL_ 112    // TOPK_*CB_
#define SCALE 0.15617376188860607f  // 1/sqrt(41)

typedef unsigned short bfu;

__device__ __forceinline__ float b2f(bfu h) {
    union { unsigned u; float f; } c; c.u = ((unsigned)h) << 16; return c.f;
}
__device__ __forceinline__ bfu f2b(float f) {
    union { float f; unsigned u; } c; c.f = f;
    unsigned u = c.u;
    return (bfu)((u + 0x7fffu + ((u >> 16) & 1u)) >> 16);
}
__device__ __forceinline__ void b2x2(unsigned u, float& a, float& b) {
    union { unsigned u; float f; } c0, c1;
    c0.u = u << 16; c1.u = u & 0xffff0000u;
    a = c0.f; b = c1.f;
}

// ---------------- workspace layout (bytes) — per-batch reuse, ~32.9 MB total ----------------
#define NHLD ((size_t)H_ * L_ * D_)        // 2,939,280 elems (one batch)
#define NHCD ((size_t)H_ * LC_ * D_)       // 419,840 elems
#define OFF_R1   ((size_t)0)                         // fp32 (k32 then q32)
#define OFF_V32  (OFF_R1  + NHLD * 4)
#define OFF_K16  (OFF_V32 + NHLD * 4)                // bf16
#define OFF_KC   (OFF_K16 + NHLD * 2)                // fp32
#define OFF_VC   (OFF_KC  + NHCD * 4)                // fp32
#define OFF_BS   (OFF_VC  + NHCD * 4)                // fp64
#define OFF_IDX  (OFF_BS  + (size_t)H_ * LC_ * 8)    // int
#define WS_NEEDED (OFF_IDX + (size_t)H_ * TOPK_ * 4)

// ================= K-fail: zero the output (diagnostic fallback) =================
__global__ __launch_bounds__(256) void k_fail(float* __restrict__ out, int n) {
    int i = blockIdx.x * 256 + threadIdx.x;
    if (i < n) out[i] = 0.f;
}

// ================= K0: zero block scores (double) =================
__global__ __launch_bounds__(256) void k_zero_d(double* __restrict__ p, int n) {
    int i = blockIdx.x * 256 + threadIdx.x;
    if (i < n) p[i] = 0.0;
}

// ================= K1 v2: projection, 2 cols/thread, optional 2 matrices via z ======
// grid (224, 2, nz), block 256. 16 rows x 512 cols per block.
__global__ __launch_bounds__(256) void k_proj2(
    const float* __restrict__ x,
    const float* __restrict__ wA, const float* __restrict__ bA, float* __restrict__ outA,
    const float* __restrict__ wB, const float* __restrict__ bB, float* __restrict__ outB,
    int b)
{
    __shared__ float xs[E_ * 17];   // transposed [e][r], stride 17, 55,760 B
    const float* w    = (blockIdx.z == 0) ? wA : wB;
    const float* bias = (blockIdx.z == 0) ? bA : bB;
    float* outp       = (blockIdx.z == 0) ? outA : outB;
    const int row0 = blockIdx.x * 16;
    for (int i = threadIdx.x; i < 16 * E_; i += 256) {
        int r = i / E_, e = i - r * E_;
        xs[e * 17 + r] = x[((size_t)b * L_ + row0 + r) * E_ + e];
    }
    __syncthreads();
    const int c0 = blockIdx.y * 512 + threadIdx.x;   // always < 820
    const int c1 = c0 + 256;
    const bool a1 = (c1 < E_);
    const int cc1 = a1 ? c1 : (E_ - 1);
    float acc0[16], acc1[16];
    const float bb0 = bias[c0];
    const float bb1 = bias[cc1];
#pragma unroll
    for (int r = 0; r < 16; r++) { acc0[r] = bb0; acc1[r] = bb1; }
    const float* wp0 = w + c0;
    const float* wp1 = w + cc1;
#pragma unroll 2
    for (int e = 0; e < E_; e++) {
        float w0  = wp0[(size_t)e * E_];
        float w1v = wp1[(size_t)e * E_];
        const float* xr = &xs[e * 17];
#pragma unroll
        for (int r = 0; r < 16; r++) {
            acc0[r] = fmaf(xr[r], w0,  acc0[r]);
            acc1[r] = fmaf(xr[r], w1v, acc1[r]);
        }
    }
    {
        const int h = c0 / D_, d = c0 - h * D_;
#pragma unroll
        for (int r = 0; r < 16; r++)
            outp[((size_t)h * L_ + row0 + r) * D_ + d] = acc0[r];
    }
    if (a1) {
        const int h = c1 / D_, d = c1 - h * D_;
#pragma unroll
        for (int r = 0; r < 16; r++)
            outp[((size_t)h * L_ + row0 + r) * D_ + d] = acc1[r];
    }
}

// ================= K2 v2: compression MLP (fp32), 3-way split hidden phase ==========
// grid (H_*LC_/4), block 256 (4 waves, one row each)
__global__ __launch_bounds__(256) void k_cmlp(
    const float* __restrict__ src32,
    const float* __restrict__ w1, const float* __restrict__ b1,
    const float* __restrict__ w2, const float* __restrict__ b2,
    float* __restrict__ dstc, bfu* __restrict__ dst16)
{
    __shared__ float in_s[4][CB_ * D_];
    __shared__ float h_s[4][20];
    const int tid = threadIdx.x, lane = tid & 63, wave = tid >> 6;
    const int row = blockIdx.x * 4 + wave;            // h*LC_ + c
    const int h = row / LC_, c = row - h * LC_;
    const size_t base = ((size_t)h * L_ + c * CB_) * D_;
    for (int i = lane; i < CB_ * D_; i += 64) {
        float fv = src32[base + i];
        in_s[wave][i] = fv;
        if (dst16) dst16[base + i] = f2b(fv);
    }
    __syncthreads();
    if (lane < 60) {
        const int col = lane % 20, chunk = lane / 20;
        const int i0 = chunk * 96;
        const int i1 = (chunk == 2) ? (CB_ * D_) : (i0 + 96);
        float a = (chunk == 0) ? b1[col] : 0.f;
        for (int i = i0; i < i1; i++) a += in_s[wave][i] * w1[i * 20 + col];
        float aa = __shfl_down(a, 20);
        float ab = __shfl_down(a, 40);
        if (lane < 20) h_s[wave][lane] = fmaxf(a + aa + ab, 0.f);
    }
    __syncthreads();
    if (lane < D_) {
        float a = b2[lane];
#pragma unroll
        for (int j = 0; j < 20; j++) a += h_s[wave][j] * w2[j * D_ + lane];
        dstc[(size_t)row * D_ + lane] = a;
    }
}

// ================= K3 v4: compressed attention, double-buffered fp32 staging =========
// grid (20, 224), block 256. 16 queries/block, 4 per wave.
// kcs: 2 buffers x [128][44] fp32; 4 stages overlap staging with score compute.
// Region reuse after scores: bs_part f32[4][512] -> vcT bf16[41][516].
__global__ __launch_bounds__(256) void k_comp(
    const float* __restrict__ q32, const float* __restrict__ kc,
    const float* __restrict__ vc, const float* __restrict__ wg,
    const float* __restrict__ bg, float* __restrict__ outp,
    double* __restrict__ bscore, int b)
{
    __shared__ __align__(16) float kcs[2][128 * 44];  // 45,056 B
    __shared__ __align__(16) bfu p_s[16][LC_];        // 16,384 B
    __shared__ __align__(16) float q_s[16][44];       // 2,816 B
    __shared__ float g0_s[16];                        // total 64,320 B
    const int h = blockIdx.x;
    const int q0 = blockIdx.y * 16;
    const int tid = threadIdx.x, lane = tid & 63, wave = tid >> 6;
    const float* kcb = kc + (size_t)h * LC_ * D_;
    const float* vcb = vc + (size_t)h * LC_ * D_;

    for (int i = tid; i < 16 * D_; i += 256) {
        int qq = i / D_, d = i - qq * D_;
        q_s[qq][d] = q32[((size_t)h * L_ + q0 + qq) * D_ + d];
    }
    for (int i = tid; i < 128 * D_; i += 256) {   // stage 0
        int j = i / D_, d = i - j * D_;
        kcs[0][j * 44 + d] = kcb[i];
    }
    __syncthreads();

    // ---- scores over 4 stages of 128 keys, double-buffered ----
    float s[8][4];
#pragma unroll
    for (int r = 0; r < 8; r++)
#pragma unroll
        for (int qi = 0; qi < 4; qi++) s[r][qi] = 0.f;

    for (int st = 0; st < 4; st++) {
        if (st < 3) {   // prefetch next stage into the other buffer
            const float* src = kcb + (size_t)(st + 1) * 128 * D_;
            float* dst = kcs[(st + 1) & 1];
            for (int i = tid; i < 128 * D_; i += 256) {
                int j = i / D_, d = i - j * D_;
                dst[j * 44 + d] = src[i];
            }
        }
        const float* buf = kcs[st & 1];
#pragma unroll
        for (int rl = 0; rl < 2; rl++) {
            const int r = st * 2 + rl;
            const float* krow = &buf[(rl * 64 + lane) * 44];
            for (int dc = 0; dc < 10; dc++) {
                float4 kv = *(const float4*)&krow[dc * 4];
#pragma unroll
                for (int qi = 0; qi < 4; qi++) {
                    float4 qv = *(const float4*)&q_s[wave * 4 + qi][dc * 4];
                    s[r][qi] += qv.x * kv.x + qv.y * kv.y + qv.z * kv.z + qv.w * kv.w;
                }
            }
            float kt = krow[40];
#pragma unroll
            for (int qi = 0; qi < 4; qi++) s[r][qi] += q_s[wave * 4 + qi][40] * kt;
        }
        __syncthreads();
    }

    if (tid < 16) {   // gates (fp32) — q_s ready; g0_s consumed after next barrier
        float a0 = bg[0], a1 = bg[1], a2 = bg[2];
        for (int d = 0; d < D_; d++) {
            float qd = q_s[tid][d];
            a0 += qd * wg[d * 3 + 0];
            a1 += qd * wg[d * 3 + 1];
            a2 += qd * wg[d * 3 + 2];
        }
        float gm = fmaxf(a0, fmaxf(a1, a2));
        float e0 = __expf(a0 - gm), e1 = __expf(a1 - gm), e2 = __expf(a2 - gm);
        g0_s[tid] = e0 / (e0 + e1 + e2);
    }

    // ---- softmax (fp32, same numerics as R9) ----
    float bs_acc[8];
#pragma unroll
    for (int r = 0; r < 8; r++) bs_acc[r] = 0.f;
#pragma unroll
    for (int qi = 0; qi < 4; qi++) {
        float m = -1e30f;
#pragma unroll
        for (int r = 0; r < 8; r++) { s[r][qi] *= SCALE; m = fmaxf(m, s[r][qi]); }
        for (int o = 32; o; o >>= 1) m = fmaxf(m, __shfl_xor(m, o));
        float e[8], lsum = 0.f;
#pragma unroll
        for (int r = 0; r < 8; r++) { e[r] = expf(s[r][qi] - m); lsum += e[r]; }
        for (int o = 32; o; o >>= 1) lsum += __shfl_xor(lsum, o);
        float inv = 1.f / lsum;
#pragma unroll
        for (int r = 0; r < 8; r++) {
            float p = e[r] * inv;
            p_s[wave * 4 + qi][r * 64 + lane] = f2b(p);
            bs_acc[r] += p;            // fp32, pre-rounding (ranking-exact)
        }
    }

    // ---- block scores: per-wave partials (no atomics) -> global double atomics ----
    float* bs_part = (float*)kcs;      // [4][512]
#pragma unroll
    for (int r = 0; r < 8; r++) bs_part[wave * LC_ + r * 64 + lane] = bs_acc[r];
    __syncthreads();
    for (int j = tid; j < LC_; j += 256) {
        float v = bs_part[j] + bs_part[LC_ + j] + bs_part[2 * LC_ + j] + bs_part[3 * LC_ + j];
        atomicAdd(&bscore[h * LC_ + j], (double)v);
    }
    __syncthreads();                   // bs_part dead

    // ---- re-stage region as vc^T (bf16, pad 516) ----
    bfu* vcT = (bfu*)kcs;
    for (int i = tid; i < LC_ * D_; i += 256) {
        int j = i / D_, d = i - j * D_;
        vcT[d * 516 + j] = f2b(vcb[i]);
    }
    __syncthreads();

    // ---- PV -> out = g0 * attn_comp (overwrite) ----
    if (lane < D_) {
        float acc[4] = {0.f, 0.f, 0.f, 0.f};
        for (int jc = 0; jc < LC_; jc += 4) {
            uint2 vv = *(const uint2*)&vcT[lane * 516 + jc];
            float v0, v1, v2, v3;
            b2x2(vv.x, v0, v1); b2x2(vv.y, v2, v3);
#pragma unroll
            for (int qi = 0; qi < 4; qi++) {
                uint2 pp = *(const uint2*)&p_s[wave * 4 + qi][jc];
                float p0, p1, p2, p3;
                b2x2(pp.x, p0, p1); b2x2(pp.y, p2, p3);
                acc[qi] += p0 * v0 + p1 * v1 + p2 * v2 + p3 * v3;
            }
        }
#pragma unroll
        for (int qi = 0; qi < 4; qi++) {
            int row = wave * 4 + qi;
            outp[((size_t)(b * L_ + q0 + row)) * (H_ * D_) + h * D_ + lane] =
                g0_s[row] * acc[qi];
        }
    }
}

// ================= K4: top-k (per batch, fp64 scores) =================
// grid 20, block 64
__global__ __launch_bounds__(64) void k_topk(const double* __restrict__ bs, int* __restrict__ idxo)
{
    __shared__ double vb_[64];
    __shared__ int ib_[64];
    __shared__ int win;
    const int h = blockIdx.x, lane = threadIdx.x;
    double vals[8];
#pragma unroll
    for (int r = 0; r < 8; r++) vals[r] = bs[h * LC_ + r * 64 + lane];
    for (int t = 0; t < TOPK_; t++) {
        double bv = -1e30; int bi = 0x7fffffff;
#pragma unroll
        for (int r = 0; r < 8; r++) {
            int j = r * 64 + lane;
            bool better = (vals[r] > bv) || (vals[r] == bv && j < bi);
            if (better) { bv = vals[r]; bi = j; }
        }
        vb_[lane] = bv; ib_[lane] = bi;
        __syncthreads();
        if (lane == 0) {
            double best = -1e30; int besti = 0x7fffffff;
            for (int u = 0; u < 64; u++) {
                if (vb_[u] > best || (vb_[u] == best && ib_[u] < besti)) { best = vb_[u]; besti = ib_[u]; }
            }
            idxo[h * TOPK_ + t] = besti;
            win = besti;
        }
        __syncthreads();
        int w = win;
#pragma unroll
        for (int r = 0; r < 8; r++)
            if ((w >> 6) == r && (w & 63) == lane) vals[r] = -1e30;
        __syncthreads();
    }
}

// ================= K5: selected + window attention, LDS-staged (unchanged R9) ========
// grid (20, 224), block 256. 16 queries/block, 4 per wave.
__global__ __launch_bounds__(256) void k_selwin(
    const float* __restrict__ q32, const bfu* __restrict__ k16,
    const float* __restrict__ v32, const int* __restrict__ idxp,
    const float* __restrict__ wg, const float* __restrict__ bg,
    float* __restrict__ outp, int b)
{
    __shared__ __align__(16) bfu ks_s[119][44];      // 112 sel + 7 window keys
    __shared__ __align__(16) float vsT[D_][130];     // fp32 v^T, pad 130
    __shared__ __align__(16) float q_s[16][44];
    __shared__ __align__(16) bfu p_s[16][NSEL_];
    __shared__ int rows_s[NSEL_];
    __shared__ float g1_s[16];
    __shared__ float pw_s[16][CB_];                  // g2-scaled window probs
    const int h = blockIdx.x;
    const int q0 = blockIdx.y * 16;
    const int tid = threadIdx.x, lane = tid & 63, wave = tid >> 6;
    const size_t kvbase = (size_t)h * L_ * D_;

    for (int i = tid; i < 16 * D_; i += 256) {
        int qq = i / D_, d = i - qq * D_;
        q_s[qq][d] = q32[((size_t)h * L_ + q0 + qq) * D_ + d];
    }
    if (tid < NSEL_) {
        int t = tid / CB_;
        rows_s[tid] = idxp[h * TOPK_ + t] * CB_ + (tid - t * CB_);
    }
    __syncthreads();

    for (int i = tid; i < 119 * D_; i += 256) {
        int key = i / D_, d = i - key * D_;
        int row = (key < NSEL_) ? rows_s[key] : (L_ - CB_ + (key - NSEL_));
        ks_s[key][d] = k16[kvbase + (size_t)row * D_ + d];
        vsT[d][key]  = v32[kvbase + (size_t)row * D_ + d];
    }
    __syncthreads();

    if (tid < 16) {   // gates + window softmax (x g2)
        float a0 = bg[0], a1 = bg[1], a2 = bg[2];
        for (int d = 0; d < D_; d++) {
            float qd = q_s[tid][d];
            a0 += qd * wg[d * 3 + 0];
            a1 += qd * wg[d * 3 + 1];
            a2 += qd * wg[d * 3 + 2];
        }
        float gm = fmaxf(a0, fmaxf(a1, a2));
        float e0 = __expf(a0 - gm), e1 = __expf(a1 - gm), e2 = __expf(a2 - gm);
        float ginv = 1.f / (e0 + e1 + e2);
        g1_s[tid] = e1 * ginv;
        float g2 = e2 * ginv;
        float sw[CB_];
        float m = -1e30f;
        for (int i = 0; i < CB_; i++) {
            float ss = 0.f;
            for (int d = 0; d < D_; d++) ss += q_s[tid][d] * b2f(ks_s[NSEL_ + i][d]);
            sw[i] = ss * SCALE;
            m = fmaxf(m, sw[i]);
        }
        float lsum = 0.f;
        for (int i = 0; i < CB_; i++) { sw[i] = __expf(sw[i] - m); lsum += sw[i]; }
        float winv = g2 / lsum;
        for (int i = 0; i < CB_; i++) pw_s[tid][i] = sw[i] * winv;
    }
    __syncthreads();

    const bool v1 = (64 + lane) < NSEL_;
    const int row1c = v1 ? (64 + lane) : 0;
    float s0[4] = {0, 0, 0, 0}, s1[4] = {0, 0, 0, 0};
    for (int dc = 0; dc < 10; dc++) {
        float4 qv[4];
#pragma unroll
        for (int qi = 0; qi < 4; qi++) qv[qi] = *(const float4*)&q_s[wave * 4 + qi][dc * 4];
        uint2 ra = *(const uint2*)&ks_s[lane][dc * 4];
        uint2 rb = *(const uint2*)&ks_s[row1c][dc * 4];
        float a0, a1, a2, a3, c0, c1, c2, c3;
        b2x2(ra.x, a0, a1); b2x2(ra.y, a2, a3);
        b2x2(rb.x, c0, c1); b2x2(rb.y, c2, c3);
#pragma unroll
        for (int qi = 0; qi < 4; qi++) {
            s0[qi] += qv[qi].x * a0 + qv[qi].y * a1 + qv[qi].z * a2 + qv[qi].w * a3;
            s1[qi] += qv[qi].x * c0 + qv[qi].y * c1 + qv[qi].z * c2 + qv[qi].w * c3;
        }
    }
    {
        float ka = b2f(ks_s[lane][40]);
        float kb = b2f(ks_s[row1c][40]);
#pragma unroll
        for (int qi = 0; qi < 4; qi++) {
            float qt = q_s[wave * 4 + qi][40];
            s0[qi] += qt * ka; s1[qi] += qt * kb;
        }
    }
#pragma unroll
    for (int qi = 0; qi < 4; qi++) {
        float a0 = s0[qi] * SCALE;
        float a1 = v1 ? s1[qi] * SCALE : -1e30f;
        float m = fmaxf(a0, a1);
        for (int o = 32; o; o >>= 1) m = fmaxf(m, __shfl_xor(m, o));
        float e0 = __expf(a0 - m);
        float e1 = v1 ? __expf(a1 - m) : 0.f;
        float lsum = e0 + e1;
        for (int o = 32; o; o >>= 1) lsum += __shfl_xor(lsum, o);
        float inv = 1.f / lsum;
        p_s[wave * 4 + qi][lane] = f2b(e0 * inv);
        if (v1) p_s[wave * 4 + qi][64 + lane] = f2b(e1 * inv);
    }
    __syncthreads();

    if (lane < D_) {
        float acc[4] = {0, 0, 0, 0};
        for (int jc = 0; jc < NSEL_; jc += 4) {
            float2 va = *(const float2*)&vsT[lane][jc];
            float2 vb = *(const float2*)&vsT[lane][jc + 2];
#pragma unroll
            for (int qi = 0; qi < 4; qi++) {
                uint2 pp = *(const uint2*)&p_s[wave * 4 + qi][jc];
                float p0, p1, p2, p3;
                b2x2(pp.x, p0, p1); b2x2(pp.y, p2, p3);
                acc[qi] += p0 * va.x + p1 * va.y + p2 * vb.x + p3 * vb.y;
            }
        }
#pragma unroll
        for (int qi = 0; qi < 4; qi++) {
            int row = wave * 4 + qi;
            float wvv = 0.f;
#pragma unroll
            for (int i = 0; i < CB_; i++) wvv += pw_s[row][i] * vsT[lane][NSEL_ + i];
            float* op = &outp[((size_t)(b * L_ + q0 + row)) * (H_ * D_) + h * D_ + lane];
            *op = *op + g1_s[row] * acc[qi] + wvv;
        }
    }
}

extern "C" void kernel_launch(void* const* d_in, const int* in_sizes, int n_in,
                              void* d_out, int out_size, void* d_ws, size_t ws_size,
                              hipStream_t stream) {
    (void)in_sizes; (void)n_in;
    const float* x  = (const float*)d_in[0];
    const float* wq = (const float*)d_in[1];  const float* bq = (const float*)d_in[2];
    const float* wk = (const float*)d_in[3];  const float* bk = (const float*)d_in[4];
    const float* wv = (const float*)d_in[5];  const float* bv = (const float*)d_in[6];
    const float* w1 = (const float*)d_in[7];  const float* b1 = (const float*)d_in[8];
    const float* w2 = (const float*)d_in[9];  const float* b2 = (const float*)d_in[10];
    const float* wg = (const float*)d_in[11]; const float* bg = (const float*)d_in[12];

    if (d_ws == nullptr || ws_size < WS_NEEDED) {
        k_fail<<<dim3((out_size + 255) / 256), 256, 0, stream>>>((float*)d_out, out_size);
        return;
    }

    char* ws = (char*)d_ws;
    float*  r1   = (float*)(ws + OFF_R1);    // k32 then q32
    float*  v32  = (float*)(ws + OFF_V32);
    bfu*    k16  = (bfu*)(ws + OFF_K16);
    float*  kc   = (float*)(ws + OFF_KC);
    float*  vc   = (float*)(ws + OFF_VC);
    double* bsc  = (double*)(ws + OFF_BS);
    int*    idxp = (int*)(ws + OFF_IDX);
    float*  outp = (float*)d_out;

    for (int b = 0; b < B_; b++) {
        k_zero_d<<<dim3((H_ * LC_ + 255) / 256), 256, 0, stream>>>(bsc, H_ * LC_);
        // K -> r1 and V -> v32 in one fused launch
        k_proj2<<<dim3(L_ / 16, 2, 2), 256, 0, stream>>>(x, wk, bk, r1, wv, bv, v32, b);
        k_cmlp<<<dim3(H_ * LC_ / 4), 256, 0, stream>>>(r1, w1, b1, w2, b2, kc, k16);
        // Q -> r1 (overwrites k32; cmlpK done)
        k_proj2<<<dim3(L_ / 16, 2, 1), 256, 0, stream>>>(x, wq, bq, r1, wq, bq, r1, b);
        k_cmlp<<<dim3(H_ * LC_ / 4), 256, 0, stream>>>(v32, w1, b1, w2, b2, vc, (bfu*)nullptr);
        k_comp<<<dim3(H_, L_ / 16), 256, 0, stream>>>(r1, kc, vc, wg, bg, outp, bsc, b);
        k_topk<<<dim3(H_), 64, 0, stream>>>(bsc, idxp);
        k_selwin<<<dim3(H_, L_ / 16), 256, 0, stream>>>(r1, k16, v32, idxp, wg, bg, outp, b);
    }
}

// Round 11
// 2154.081 us; speedup vs baseline: 4.3948x; 1.2309x over previous
//
#include <hip/hip_runtime.h>

#define B_ 2
#define L_ 3584
#define E_ 820
#define H_ 20
#define D_ 41
#define CB_ 7
#define LC_ 512      // L_/CB_
#define TOPK_ 16
#define NSEL_ 112    // TOPK_*CB_
#define SCALE 0.15617376188860607f  // 1/sqrt(41)

typedef unsigned short bfu;

__device__ __forceinline__ float b2f(bfu h) {
    union { unsigned u; float f; } c; c.u = ((unsigned)h) << 16; return c.f;
}
__device__ __forceinline__ bfu f2b(float f) {
    union { float f; unsigned u; } c; c.f = f;
    unsigned u = c.u;
    return (bfu)((u + 0x7fffu + ((u >> 16) & 1u)) >> 16);
}
__device__ __forceinline__ void b2x2(unsigned u, float& a, float& b) {
    union { unsigned u; float f; } c0, c1;
    c0.u = u << 16; c1.u = u & 0xffff0000u;
    a = c0.f; b = c1.f;
}

// ---------------- workspace layout (bytes) — per-batch reuse, ~32.9 MB total ----------------
#define NHLD ((size_t)H_ * L_ * D_)
#define NHCD ((size_t)H_ * LC_ * D_)
#define OFF_R1   ((size_t)0)                         // fp32 (k32 then q32)
#define OFF_V32  (OFF_R1  + NHLD * 4)
#define OFF_K16  (OFF_V32 + NHLD * 4)                // bf16
#define OFF_KC   (OFF_K16 + NHLD * 2)                // fp32
#define OFF_VC   (OFF_KC  + NHCD * 4)                // fp32
#define OFF_BS   (OFF_VC  + NHCD * 4)                // fp64
#define OFF_IDX  (OFF_BS  + (size_t)H_ * LC_ * 8)    // int
#define WS_NEEDED (OFF_IDX + (size_t)H_ * TOPK_ * 4)

// ================= K-fail =================
__global__ __launch_bounds__(256) void k_fail(float* __restrict__ out, int n) {
    int i = blockIdx.x * 256 + threadIdx.x;
    if (i < n) out[i] = 0.f;
}

// ================= K0: zero block scores (double) =================
__global__ __launch_bounds__(256) void k_zero_d(double* __restrict__ p, int n) {
    int i = blockIdx.x * 256 + threadIdx.x;
    if (i < n) p[i] = 0.0;
}

// ================= K1 v3: projection, 2 cols/thread, xs in 2 E-halves (27.9 KB LDS) ===
// grid (224, 2, nz), block 256. 16 rows x 512 cols per block.
__global__ __launch_bounds__(256) void k_proj2(
    const float* __restrict__ x,
    const float* __restrict__ wA, const float* __restrict__ bA, float* __restrict__ outA,
    const float* __restrict__ wB, const float* __restrict__ bB, float* __restrict__ outB,
    int b)
{
    __shared__ float xs[410 * 17];   // 27,880 B
    const float* w    = (blockIdx.z == 0) ? wA : wB;
    const float* bias = (blockIdx.z == 0) ? bA : bB;
    float* outp       = (blockIdx.z == 0) ? outA : outB;
    const int row0 = blockIdx.x * 16;
    const int c0 = blockIdx.y * 512 + threadIdx.x;   // always < 820
    const int c1 = c0 + 256;
    const bool a1 = (c1 < E_);
    const int cc1 = a1 ? c1 : (E_ - 1);
    float acc0[16], acc1[16];
    const float bb0 = bias[c0];
    const float bb1 = bias[cc1];
#pragma unroll
    for (int r = 0; r < 16; r++) { acc0[r] = bb0; acc1[r] = bb1; }

    for (int half = 0; half < 2; half++) {
        for (int i = threadIdx.x; i < 16 * 410; i += 256) {
            int r = i / 410, e = i - r * 410;
            xs[e * 17 + r] = x[((size_t)b * L_ + row0 + r) * E_ + half * 410 + e];
        }
        __syncthreads();
        const float* wp0 = w + (size_t)half * 410 * E_ + c0;
        const float* wp1 = w + (size_t)half * 410 * E_ + cc1;
#pragma unroll 2
        for (int e = 0; e < 410; e++) {
            float w0  = wp0[(size_t)e * E_];
            float w1v = wp1[(size_t)e * E_];
            const float* xr = &xs[e * 17];
#pragma unroll
            for (int r = 0; r < 16; r++) {
                acc0[r] = fmaf(xr[r], w0,  acc0[r]);
                acc1[r] = fmaf(xr[r], w1v, acc1[r]);
            }
        }
        __syncthreads();
    }
    {
        const int h = c0 / D_, d = c0 - h * D_;
#pragma unroll
        for (int r = 0; r < 16; r++)
            outp[((size_t)h * L_ + row0 + r) * D_ + d] = acc0[r];
    }
    if (a1) {
        const int h = c1 / D_, d = c1 - h * D_;
#pragma unroll
        for (int r = 0; r < 16; r++)
            outp[((size_t)h * L_ + row0 + r) * D_ + d] = acc1[r];
    }
}

// ================= K2: compression MLP (fp32), 3-way split hidden phase ==========
// grid (H_*LC_/4), block 256 (4 waves, one row each)
__global__ __launch_bounds__(256) void k_cmlp(
    const float* __restrict__ src32,
    const float* __restrict__ w1, const float* __restrict__ b1,
    const float* __restrict__ w2, const float* __restrict__ b2,
    float* __restrict__ dstc, bfu* __restrict__ dst16)
{
    __shared__ float in_s[4][CB_ * D_];
    __shared__ float h_s[4][20];
    const int tid = threadIdx.x, lane = tid & 63, wave = tid >> 6;
    const int row = blockIdx.x * 4 + wave;            // h*LC_ + c
    const int h = row / LC_, c = row - h * LC_;
    const size_t base = ((size_t)h * L_ + c * CB_) * D_;
    for (int i = lane; i < CB_ * D_; i += 64) {
        float fv = src32[base + i];
        in_s[wave][i] = fv;
        if (dst16) dst16[base + i] = f2b(fv);
    }
    __syncthreads();
    if (lane < 60) {
        const int col = lane % 20, chunk = lane / 20;
        const int i0 = chunk * 96;
        const int i1 = (chunk == 2) ? (CB_ * D_) : (i0 + 96);
        float a = (chunk == 0) ? b1[col] : 0.f;
        for (int i = i0; i < i1; i++) a += in_s[wave][i] * w1[i * 20 + col];
        float aa = __shfl_down(a, 20);
        float ab = __shfl_down(a, 40);
        if (lane < 20) h_s[wave][lane] = fmaxf(a + aa + ab, 0.f);
    }
    __syncthreads();
    if (lane < D_) {
        float a = b2[lane];
#pragma unroll
        for (int j = 0; j < 20; j++) a += h_s[wave][j] * w2[j * D_ + lane];
        dstc[(size_t)row * D_ + lane] = a;
    }
}

// ================= K3 v5: compressed attention, 32 queries/block =================
// grid (20, 112), block 256. Wave owns 8 queries; lane owns keys r*64+lane (r=0..7).
// kcs single buffer [128][44] fp32, 4 stages. PV: vc^T in 2 half-key passes.
__global__ __launch_bounds__(256) void k_comp(
    const float* __restrict__ q32, const float* __restrict__ kc,
    const float* __restrict__ vc, const float* __restrict__ wg,
    const float* __restrict__ bg, float* __restrict__ outp,
    double* __restrict__ bscore, int b)
{
    __shared__ __align__(16) float kcs[128 * 44];     // 22,528 B (reused: bs_part, vcT)
    __shared__ __align__(16) bfu p_s[32][LC_];        // 32,768 B
    __shared__ __align__(16) float q_s[32][44];       // 5,632 B
    __shared__ float g0_s[32];                        // total 61,056 B
    const int h = blockIdx.x;
    const int q0 = blockIdx.y * 32;
    const int tid = threadIdx.x, lane = tid & 63, wave = tid >> 6;
    const float* kcb = kc + (size_t)h * LC_ * D_;
    const float* vcb = vc + (size_t)h * LC_ * D_;

    for (int i = tid; i < 32 * D_; i += 256) {
        int qq = i / D_, d = i - qq * D_;
        q_s[qq][d] = q32[((size_t)h * L_ + q0 + qq) * D_ + d];
    }
    __syncthreads();

    if (tid < 32) {   // gates (fp32)
        float a0 = bg[0], a1 = bg[1], a2 = bg[2];
        for (int d = 0; d < D_; d++) {
            float qd = q_s[tid][d];
            a0 += qd * wg[d * 3 + 0];
            a1 += qd * wg[d * 3 + 1];
            a2 += qd * wg[d * 3 + 2];
        }
        float gm = fmaxf(a0, fmaxf(a1, a2));
        float e0 = __expf(a0 - gm), e1 = __expf(a1 - gm), e2 = __expf(a2 - gm);
        g0_s[tid] = e0 / (e0 + e1 + e2);
    }

    // ---- scores (fp32 kc): 4 stages of 128 keys, single buffer ----
    float s[8][8];
#pragma unroll
    for (int r = 0; r < 8; r++)
#pragma unroll
        for (int qi = 0; qi < 8; qi++) s[r][qi] = 0.f;

    for (int st = 0; st < 4; st++) {
        for (int i = tid; i < 128 * D_; i += 256) {
            int j = i / D_, d = i - j * D_;
            kcs[j * 44 + d] = kcb[(size_t)st * 128 * D_ + i];
        }
        __syncthreads();
        const int r0 = st * 2, r1 = r0 + 1;
        for (int dc = 0; dc < 10; dc++) {
            float4 qv[8];
#pragma unroll
            for (int qi = 0; qi < 8; qi++) qv[qi] = *(const float4*)&q_s[wave * 8 + qi][dc * 4];
            float4 k0 = *(const float4*)&kcs[lane * 44 + dc * 4];
            float4 k1 = *(const float4*)&kcs[(64 + lane) * 44 + dc * 4];
#pragma unroll
            for (int qi = 0; qi < 8; qi++) {
                s[r0][qi] += qv[qi].x * k0.x + qv[qi].y * k0.y + qv[qi].z * k0.z + qv[qi].w * k0.w;
                s[r1][qi] += qv[qi].x * k1.x + qv[qi].y * k1.y + qv[qi].z * k1.z + qv[qi].w * k1.w;
            }
        }
        {   // tail d = 40
            float kt0 = kcs[lane * 44 + 40];
            float kt1 = kcs[(64 + lane) * 44 + 40];
#pragma unroll
            for (int qi = 0; qi < 8; qi++) {
                float qt = q_s[wave * 8 + qi][40];
                s[r0][qi] += qt * kt0;
                s[r1][qi] += qt * kt1;
            }
        }
        __syncthreads();   // compute done before next stage overwrites kcs
    }

    // ---- softmax (fp32, ranking-exact) ----
    float bs_acc[8];
#pragma unroll
    for (int r = 0; r < 8; r++) bs_acc[r] = 0.f;
#pragma unroll
    for (int qi = 0; qi < 8; qi++) {
        float m = -1e30f;
#pragma unroll
        for (int r = 0; r < 8; r++) { s[r][qi] *= SCALE; m = fmaxf(m, s[r][qi]); }
        for (int o = 32; o; o >>= 1) m = fmaxf(m, __shfl_xor(m, o));
        float e[8], lsum = 0.f;
#pragma unroll
        for (int r = 0; r < 8; r++) { e[r] = expf(s[r][qi] - m); lsum += e[r]; }
        for (int o = 32; o; o >>= 1) lsum += __shfl_xor(lsum, o);
        float inv = 1.f / lsum;
#pragma unroll
        for (int r = 0; r < 8; r++) {
            float p = e[r] * inv;
            p_s[wave * 8 + qi][r * 64 + lane] = f2b(p);
            bs_acc[r] += p;
        }
    }

    // ---- block scores: per-wave partials in dead kcs -> global double atomics ----
    float* bs_part = (float*)kcs;      // [4][512]
#pragma unroll
    for (int r = 0; r < 8; r++) bs_part[wave * LC_ + r * 64 + lane] = bs_acc[r];
    __syncthreads();
    for (int j = tid; j < LC_; j += 256) {
        float v = bs_part[j] + bs_part[LC_ + j] + bs_part[2 * LC_ + j] + bs_part[3 * LC_ + j];
        atomicAdd(&bscore[h * LC_ + j], (double)v);
    }
    __syncthreads();                   // bs_part dead

    // ---- PV: vc^T staged in 2 half-key passes (bf16, [41][260]) ----
    bfu* vcT = (bfu*)kcs;              // 41*260*2 = 21,320 B <= 22,528
    float acc[8];
#pragma unroll
    for (int qi = 0; qi < 8; qi++) acc[qi] = 0.f;
    for (int half = 0; half < 2; half++) {
        for (int i = tid; i < 256 * D_; i += 256) {
            int j = i / D_, d = i - j * D_;
            vcT[d * 260 + j] = f2b(vcb[(size_t)(half * 256 + j) * D_ + d]);
        }
        __syncthreads();
        if (lane < D_) {
            for (int jc = 0; jc < 256; jc += 4) {
                uint2 vv = *(const uint2*)&vcT[lane * 260 + jc];
                float v0, v1, v2, v3;
                b2x2(vv.x, v0, v1); b2x2(vv.y, v2, v3);
#pragma unroll
                for (int qi = 0; qi < 8; qi++) {
                    uint2 pp = *(const uint2*)&p_s[wave * 8 + qi][half * 256 + jc];
                    float p0, p1, p2, p3;
                    b2x2(pp.x, p0, p1); b2x2(pp.y, p2, p3);
                    acc[qi] += p0 * v0 + p1 * v1 + p2 * v2 + p3 * v3;
                }
            }
        }
        __syncthreads();
    }
    if (lane < D_) {
#pragma unroll
        for (int qi = 0; qi < 8; qi++) {
            int row = wave * 8 + qi;
            outp[((size_t)(b * L_ + q0 + row)) * (H_ * D_) + h * D_ + lane] =
                g0_s[row] * acc[qi];
        }
    }
}

// ================= K4: top-k (per batch, fp64 scores) =================
// grid 20, block 64
__global__ __launch_bounds__(64) void k_topk(const double* __restrict__ bs, int* __restrict__ idxo)
{
    __shared__ double vb_[64];
    __shared__ int ib_[64];
    __shared__ int win;
    const int h = blockIdx.x, lane = threadIdx.x;
    double vals[8];
#pragma unroll
    for (int r = 0; r < 8; r++) vals[r] = bs[h * LC_ + r * 64 + lane];
    for (int t = 0; t < TOPK_; t++) {
        double bv = -1e30; int bi = 0x7fffffff;
#pragma unroll
        for (int r = 0; r < 8; r++) {
            int j = r * 64 + lane;
            bool better = (vals[r] > bv) || (vals[r] == bv && j < bi);
            if (better) { bv = vals[r]; bi = j; }
        }
        vb_[lane] = bv; ib_[lane] = bi;
        __syncthreads();
        if (lane == 0) {
            double best = -1e30; int besti = 0x7fffffff;
            for (int u = 0; u < 64; u++) {
                if (vb_[u] > best || (vb_[u] == best && ib_[u] < besti)) { best = vb_[u]; besti = ib_[u]; }
            }
            idxo[h * TOPK_ + t] = besti;
            win = besti;
        }
        __syncthreads();
        int w = win;
#pragma unroll
        for (int r = 0; r < 8; r++)
            if ((w >> 6) == r && (w & 63) == lane) vals[r] = -1e30;
        __syncthreads();
    }
}

// ================= K5 v3: selected + window attention, 32 queries/block ==============
// grid (20, 112), block 256. Wave owns 8 queries in 2 groups of 4.
__global__ __launch_bounds__(256) void k_selwin(
    const float* __restrict__ q32, const bfu* __restrict__ k16,
    const float* __restrict__ v32, const int* __restrict__ idxp,
    const float* __restrict__ wg, const float* __restrict__ bg,
    float* __restrict__ outp, int b)
{
    __shared__ __align__(16) bfu ks_s[119][44];      // 112 sel + 7 window keys
    __shared__ __align__(16) float vsT[D_][130];     // fp32 v^T, pad 130
    __shared__ __align__(16) float q_s[32][44];
    __shared__ __align__(16) bfu p_s[32][NSEL_];
    __shared__ int rows_s[NSEL_];
    __shared__ float g1_s[32];
    __shared__ float pw_s[32][CB_];                  // g2-scaled window probs
    const int h = blockIdx.x;
    const int q0 = blockIdx.y * 32;
    const int tid = threadIdx.x, lane = tid & 63, wave = tid >> 6;
    const size_t kvbase = (size_t)h * L_ * D_;

    for (int i = tid; i < 32 * D_; i += 256) {
        int qq = i / D_, d = i - qq * D_;
        q_s[qq][d] = q32[((size_t)h * L_ + q0 + qq) * D_ + d];
    }
    if (tid < NSEL_) {
        int t = tid / CB_;
        rows_s[tid] = idxp[h * TOPK_ + t] * CB_ + (tid - t * CB_);
    }
    __syncthreads();

    for (int i = tid; i < 119 * D_; i += 256) {
        int key = i / D_, d = i - key * D_;
        int row = (key < NSEL_) ? rows_s[key] : (L_ - CB_ + (key - NSEL_));
        ks_s[key][d] = k16[kvbase + (size_t)row * D_ + d];
        vsT[d][key]  = v32[kvbase + (size_t)row * D_ + d];
    }
    __syncthreads();

    if (tid < 32) {   // gates + window softmax (x g2)
        float a0 = bg[0], a1 = bg[1], a2 = bg[2];
        for (int d = 0; d < D_; d++) {
            float qd = q_s[tid][d];
            a0 += qd * wg[d * 3 + 0];
            a1 += qd * wg[d * 3 + 1];
            a2 += qd * wg[d * 3 + 2];
        }
        float gm = fmaxf(a0, fmaxf(a1, a2));
        float e0 = __expf(a0 - gm), e1 = __expf(a1 - gm), e2 = __expf(a2 - gm);
        float ginv = 1.f / (e0 + e1 + e2);
        g1_s[tid] = e1 * ginv;
        float g2 = e2 * ginv;
        float sw[CB_];
        float m = -1e30f;
        for (int i = 0; i < CB_; i++) {
            float ss = 0.f;
            for (int d = 0; d < D_; d++) ss += q_s[tid][d] * b2f(ks_s[NSEL_ + i][d]);
            sw[i] = ss * SCALE;
            m = fmaxf(m, sw[i]);
        }
        float lsum = 0.f;
        for (int i = 0; i < CB_; i++) { sw[i] = __expf(sw[i] - m); lsum += sw[i]; }
        float winv = g2 / lsum;
        for (int i = 0; i < CB_; i++) pw_s[tid][i] = sw[i] * winv;
    }
    __syncthreads();

    const bool v1 = (64 + lane) < NSEL_;
    const int row1c = v1 ? (64 + lane) : 0;
    for (int g = 0; g < 2; g++) {
        const int qb = wave * 8 + g * 4;
        float s0[4] = {0, 0, 0, 0}, s1[4] = {0, 0, 0, 0};
        for (int dc = 0; dc < 10; dc++) {
            float4 qv[4];
#pragma unroll
            for (int qi = 0; qi < 4; qi++) qv[qi] = *(const float4*)&q_s[qb + qi][dc * 4];
            uint2 ra = *(const uint2*)&ks_s[lane][dc * 4];
            uint2 rb = *(const uint2*)&ks_s[row1c][dc * 4];
            float a0, a1, a2, a3, c0, c1, c2, c3;
            b2x2(ra.x, a0, a1); b2x2(ra.y, a2, a3);
            b2x2(rb.x, c0, c1); b2x2(rb.y, c2, c3);
#pragma unroll
            for (int qi = 0; qi < 4; qi++) {
                s0[qi] += qv[qi].x * a0 + qv[qi].y * a1 + qv[qi].z * a2 + qv[qi].w * a3;
                s1[qi] += qv[qi].x * c0 + qv[qi].y * c1 + qv[qi].z * c2 + qv[qi].w * c3;
            }
        }
        {
            float ka = b2f(ks_s[lane][40]);
            float kb = b2f(ks_s[row1c][40]);
#pragma unroll
            for (int qi = 0; qi < 4; qi++) {
                float qt = q_s[qb + qi][40];
                s0[qi] += qt * ka; s1[qi] += qt * kb;
            }
        }
#pragma unroll
        for (int qi = 0; qi < 4; qi++) {
            float a0 = s0[qi] * SCALE;
            float a1 = v1 ? s1[qi] * SCALE : -1e30f;
            float m = fmaxf(a0, a1);
            for (int o = 32; o; o >>= 1) m = fmaxf(m, __shfl_xor(m, o));
            float e0 = __expf(a0 - m);
            float e1 = v1 ? __expf(a1 - m) : 0.f;
            float lsum = e0 + e1;
            for (int o = 32; o; o >>= 1) lsum += __shfl_xor(lsum, o);
            float inv = 1.f / lsum;
            p_s[qb + qi][lane] = f2b(e0 * inv);
            if (v1) p_s[qb + qi][64 + lane] = f2b(e1 * inv);
        }
    }
    __syncthreads();

    if (lane < D_) {
        for (int g = 0; g < 2; g++) {
            const int qb = wave * 8 + g * 4;
            float acc[4] = {0, 0, 0, 0};
            for (int jc = 0; jc < NSEL_; jc += 4) {
                float2 va = *(const float2*)&vsT[lane][jc];
                float2 vb = *(const float2*)&vsT[lane][jc + 2];
#pragma unroll
                for (int qi = 0; qi < 4; qi++) {
                    uint2 pp = *(const uint2*)&p_s[qb + qi][jc];
                    float p0, p1, p2, p3;
                    b2x2(pp.x, p0, p1); b2x2(pp.y, p2, p3);
                    acc[qi] += p0 * va.x + p1 * va.y + p2 * vb.x + p3 * vb.y;
                }
            }
#pragma unroll
            for (int qi = 0; qi < 4; qi++) {
                int row = qb + qi;
                float wvv = 0.f;
#pragma unroll
                for (int i = 0; i < CB_; i++) wvv += pw_s[row][i] * vsT[lane][NSEL_ + i];
                float* op = &outp[((size_t)(b * L_ + q0 + row)) * (H_ * D_) + h * D_ + lane];
                *op = *op + g1_s[row] * acc[qi] + wvv;
            }
        }
    }
}

extern "C" void kernel_launch(void* const* d_in, const int* in_sizes, int n_in,
                              void* d_out, int out_size, void* d_ws, size_t ws_size,
                              hipStream_t stream) {
    (void)in_sizes; (void)n_in;
    const float* x  = (const float*)d_in[0];
    const float* wq = (const float*)d_in[1];  const float* bq = (const float*)d_in[2];
    const float* wk = (const float*)d_in[3];  const float* bk = (const float*)d_in[4];
    const float* wv = (const float*)d_in[5];  const float* bv = (const float*)d_in[6];
    const float* w1 = (const float*)d_in[7];  const float* b1 = (const float*)d_in[8];
    const float* w2 = (const float*)d_in[9];  const float* b2 = (const float*)d_in[10];
    const float* wg = (const float*)d_in[11]; const float* bg = (const float*)d_in[12];

    if (d_ws == nullptr || ws_size < WS_NEEDED) {
        k_fail<<<dim3((out_size + 255) / 256), 256, 0, stream>>>((float*)d_out, out_size);
        return;
    }

    char* ws = (char*)d_ws;
    float*  r1   = (float*)(ws + OFF_R1);    // k32 then q32
    float*  v32  = (float*)(ws + OFF_V32);
    bfu*    k16  = (bfu*)(ws + OFF_K16);
    float*  kc   = (float*)(ws + OFF_KC);
    float*  vc   = (float*)(ws + OFF_VC);
    double* bsc  = (double*)(ws + OFF_BS);
    int*    idxp = (int*)(ws + OFF_IDX);
    float*  outp = (float*)d_out;

    for (int b = 0; b < B_; b++) {
        k_zero_d<<<dim3((H_ * LC_ + 255) / 256), 256, 0, stream>>>(bsc, H_ * LC_);
        // K -> r1 and V -> v32 in one fused launch
        k_proj2<<<dim3(L_ / 16, 2, 2), 256, 0, stream>>>(x, wk, bk, r1, wv, bv, v32, b);
        k_cmlp<<<dim3(H_ * LC_ / 4), 256, 0, stream>>>(r1, w1, b1, w2, b2, kc, k16);
        // Q -> r1 (overwrites k32; cmlpK done)
        k_proj2<<<dim3(L_ / 16, 2, 1), 256, 0, stream>>>(x, wq, bq, r1, wq, bq, r1, b);
        k_cmlp<<<dim3(H_ * LC_ / 4), 256, 0, stream>>>(v32, w1, b1, w2, b2, vc, (bfu*)nullptr);
        k_comp<<<dim3(H_, L_ / 32), 256, 0, stream>>>(r1, kc, vc, wg, bg, outp, bsc, b);
        k_topk<<<dim3(H_), 64, 0, stream>>>(bsc, idxp);
        k_selwin<<<dim3(H_, L_ / 32), 256, 0, stream>>>(r1, k16, v32, idxp, wg, bg, outp, b);
    }
}